// Round 4
// baseline (196.864 us; speedup 1.0000x reference)
//
#include <hip/hip_runtime.h>

#define UNITS 4096
#define DEPTH 13
#define BATCH 256

typedef __attribute__((ext_vector_type(8))) short s16x8;
typedef __attribute__((ext_vector_type(4))) float f32x4;
typedef __attribute__((ext_vector_type(4))) int   i32x4;

__device__ __forceinline__ unsigned short f2bf(float f){
  unsigned u = __builtin_bit_cast(unsigned, f);
  u += 0x7FFFu + ((u >> 16) & 1u);
  return (unsigned short)(u >> 16);
}
__device__ __forceinline__ float bf2f(unsigned short u){
  return __builtin_bit_cast(float, ((unsigned)u) << 16);
}
__device__ __forceinline__ int levelof(int j){ return j ? (32 - __clz(j)) : 0; }

struct Frag { s16x8 v[2][4]; };

__device__ __forceinline__ void load_afrag(Frag& f, const unsigned short* Hq,
                                           int wid, int l15, int kg){
  #pragma unroll
  for (int kk = 0; kk < 2; ++kk)
    #pragma unroll
    for (int m = 0; m < 4; ++m)
      f.v[kk][m] = *(const s16x8*)(Hq + ((size_t)((kk*4 + kg)*256 + wid*64 + m*16 + l15))*8);
}
__device__ __forceinline__ void load_bfrag(Frag& f, const unsigned short* Wk,
                                           int l15, int kg){
  #pragma unroll
  for (int kk = 0; kk < 2; ++kk)
    #pragma unroll
    for (int n = 0; n < 4; ++n)
      f.v[kk][n] = *(const s16x8*)(Wk + (n*16 + l15)*64 + kk*32 + kg*8);
}
__device__ __forceinline__ void mstep(f32x4 acc[4][4], const Frag& A, const Frag& B){
  #pragma unroll
  for (int kk = 0; kk < 2; ++kk)
    #pragma unroll
    for (int m = 0; m < 4; ++m)
      #pragma unroll
      for (int n = 0; n < 4; ++n)
        acc[m][n] = __builtin_amdgcn_mfma_f32_16x16x32_bf16(A.v[kk][m], B.v[kk][n], acc[m][n], 0, 0, 0);
}
__device__ __forceinline__ void negate(Frag& A){
  const i32x4 sgn = {(int)0x80008000, (int)0x80008000, (int)0x80008000, (int)0x80008000};
  #pragma unroll
  for (int kk = 0; kk < 2; ++kk)
    #pragma unroll
    for (int m = 0; m < 4; ++m){
      i32x4 t = __builtin_bit_cast(i32x4, A.v[kk][m]);
      t ^= sgn;
      A.v[kk][m] = __builtin_bit_cast(s16x8, t);
    }
}

// y3 epilogue: reads acc (leaves it intact), writes y3[t][p] = W3[t].relu(acc+cb2)
__device__ __forceinline__ void epilogue(const f32x4 acc[4][4], int p, int lp,
    const float* __restrict__ cb2, const float* __restrict__ W3,
    float* __restrict__ y3, int wid, int l15, int kg){
  float cbv[4];
  #pragma unroll
  for (int n = 0; n < 4; ++n) cbv[n] = cb2[(lp+1)*64 + n*16 + l15];
  int tmax = 11 - lp;
  for (int tt = 0; tt <= tmax; ++tt){
    float w30[4], w31[4];
    #pragma unroll
    for (int n = 0; n < 4; ++n){
      w30[n] = W3[(tt*2 + 0)*64 + n*16 + l15];
      w31[n] = W3[(tt*2 + 1)*64 + n*16 + l15];
    }
    int off = 4096 - (4096 >> tt);
    #pragma unroll
    for (int m = 0; m < 4; ++m)
      #pragma unroll
      for (int reg = 0; reg < 4; ++reg){
        float s0 = 0.f, s1 = 0.f;
        #pragma unroll
        for (int n = 0; n < 4; ++n){
          float hv = fmaxf(acc[m][n][reg] + cbv[n], 0.f);
          s0 = fmaf(w30[n], hv, s0);
          s1 = fmaf(w31[n], hv, s1);
        }
        #pragma unroll
        for (int d = 1; d < 16; d <<= 1){
          s0 += __shfl_xor(s0, d);
          s1 += __shfl_xor(s1, d);
        }
        if (l15 == 0){
          int b = wid*64 + m*16 + kg*4 + reg;
          float2 v; v.x = s0; v.y = s1;
          *(float2*)(y3 + ((size_t)b*4095 + off + p)*2) = v;
        }
      }
  }
}

// ---------------- K0: prep: W2->bf16, W1 B-frags, cumulative biases, w3h20 ---
__global__ __launch_bounds__(256) void k_prep(const float* __restrict__ W2,
    const float* __restrict__ W1, const float* __restrict__ W3,
    const float* __restrict__ b1, const float* __restrict__ b2, const float* __restrict__ b3,
    unsigned short* __restrict__ W2b, unsigned short* __restrict__ W1f,
    float* __restrict__ cb1, float* __restrict__ cb2, float* __restrict__ cb3,
    float* __restrict__ w3h20){
  int g = blockIdx.x * 256 + threadIdx.x;
  if (g < DEPTH*64*64) W2b[g] = f2bf(W2[g]);   // [t][out][in]
  if (blockIdx.x == 208){
    int t = threadIdx.x;
    int n = t >> 6, lane = t & 63, l15 = lane & 15, kg = lane >> 4;
    int f = n*16 + l15;
    s16x8 r = {0,0,0,0,0,0,0,0};
    #pragma unroll
    for (int j = 0; j < 4; ++j){
      int m = kg*4 + j;
      if (m < DEPTH-1){
        r[2*j]   = (short)f2bf(W1[(m*64 + f)*2]);
        r[2*j+1] = (short)f2bf(W1[(m*64 + f)*2 + 1]);
      }
    }
    *(s16x8*)(W1f + (size_t)t*8) = r;
  }
  if (blockIdx.x == 209){
    int t = threadIdx.x;
    if (t < 64){
      float r = 0.f;
      cb1[t] = 0.f;
      for (int m = 1; m < DEPTH; ++m){ r += b1[(m-1)*64 + t]; cb1[m*64 + t] = r; }
      float r2 = 0.f;
      for (int m = 0; m < DEPTH; ++m){ r2 += b2[m*64 + t]; cb2[m*64 + t] = r2; }
    } else if (t < 66){
      int o = t - 64;
      float r = 0.f;
      for (int m = 0; m < DEPTH; ++m){ r += b3[m*2 + o]; cb3[m*2 + o] = r; }
    } else if (t >= 128 && t < 128 + DEPTH*2){
      int q = t - 128, tt = q >> 1, o = q & 1;
      float s = 0.f;
      for (int f = 0; f < 64; ++f)
        s = fmaf(W3[(tt*2 + o)*64 + f], fmaxf(b2[f], 0.f), s);  // h2[0]=relu(b2[0][:])
      w3h20[tt*2 + o] = s;
    }
  }
}

// ---------------- K0b: transpose x[b][j][2] -> xT[j][b][2] -------------------
__global__ __launch_bounds__(256) void k_xpose(const float* __restrict__ x,
                                               float* __restrict__ xT){
  __shared__ float2 tile[64][65];
  int jb = (blockIdx.x & 63) * 64;
  int bb = (blockIdx.x >> 6) * 64;
  int t = threadIdx.x;
  #pragma unroll
  for (int i = 0; i < 16; ++i){
    int idx = i*256 + t;
    int jj = idx & 63, b = idx >> 6;
    tile[jj][b] = *(const float2*)(x + (((size_t)(bb + b))*UNITS + jb + jj)*2);
  }
  __syncthreads();
  #pragma unroll
  for (int i = 0; i < 16; ++i){
    int idx = i*256 + t;
    int b = idx & 63, jj = idx >> 6;
    *(float2*)(xT + (((size_t)(jb + jj))*BATCH + bb + b)*2) = tile[jj][b];
  }
}

// ---------------- K1: H[p] = relu(sum_m W1[m].x[p>>m] + cb1[lvl(p)+1]) -------
// Stored in MFMA-A-fragment tiled layout: idx16 = ((kk*4+kg)*256 + row)*8 + e
__global__ __launch_bounds__(256) void k_GH(const float* __restrict__ xT,
    const unsigned short* __restrict__ W1f, const float* __restrict__ cb1,
    unsigned short* __restrict__ H){
  __shared__ unsigned short tile[BATCH*64];  // 32 KiB
  int p = blockIdx.x;
  int lvl = levelof(p);
  int t = threadIdx.x, wid = t >> 6, lane = t & 63, l15 = lane & 15, kg = lane >> 4;

  s16x8 af[4];
  #pragma unroll
  for (int m = 0; m < 4; ++m){
    int b = wid*64 + m*16 + l15;
    s16x8 r = {0,0,0,0,0,0,0,0};
    #pragma unroll
    for (int j = 0; j < 4; ++j){
      int mm = kg*4 + j;
      if (mm <= lvl){
        float2 xv = *(const float2*)(xT + ((size_t)(p >> mm)*BATCH + b)*2);
        r[2*j]   = (short)f2bf(xv.x);
        r[2*j+1] = (short)f2bf(xv.y);
      }
    }
    af[m] = r;
  }
  f32x4 acc[4][4];
  #pragma unroll
  for (int m = 0; m < 4; ++m)
    #pragma unroll
    for (int n = 0; n < 4; ++n) acc[m][n] = (f32x4){0.f,0.f,0.f,0.f};
  #pragma unroll
  for (int n = 0; n < 4; ++n){
    s16x8 bf = *(const s16x8*)(W1f + ((size_t)n*64 + lane)*8);
    #pragma unroll
    for (int m = 0; m < 4; ++m)
      acc[m][n] = __builtin_amdgcn_mfma_f32_16x16x32_bf16(af[m], bf, acc[m][n], 0, 0, 0);
  }
  int lvl1 = lvl + 1;
  float cbv[4];
  #pragma unroll
  for (int n = 0; n < 4; ++n) cbv[n] = cb1[lvl1*64 + n*16 + l15];
  #pragma unroll
  for (int m = 0; m < 4; ++m)
    #pragma unroll
    for (int n = 0; n < 4; ++n)
      #pragma unroll
      for (int i = 0; i < 4; ++i){
        int row = wid*64 + m*16 + kg*4 + i;
        int col = n*16 + l15;
        float v = fmaxf(acc[m][n][i] + cbv[n], 0.f);
        *(unsigned short*)((char*)tile + ((row*128 + col*2) ^ ((row & 7) << 4))) = f2bf(v);
      }
  __syncthreads();
  #pragma unroll
  for (int i = 0; i < 8; ++i){
    s16x8 v = *(const s16x8*)((const char*)tile + ((t*128 + i*16) ^ ((t & 7) << 4)));
    *(s16x8*)(H + (size_t)p*16384 + ((size_t)i*256 + t)*8) = v;
  }
}

// ---------------- K2: quad-DFS F + fused y3 ----------------------------------
// Block q: leaves {4q..4q+3} (level L=lq+2) share chain sum_{k>=2} W2[k].H[q>>(k-2)].
// DFS with add/subtract MFMA steps (negate bf16 A-frags in-register).
__global__ __launch_bounds__(256, 2) void k_F2(const unsigned short* __restrict__ H,
    const unsigned short* __restrict__ W2b, const float* __restrict__ cb2,
    const float* __restrict__ W3, float* __restrict__ y3){
  int bid = blockIdx.x;
  int q = (bid & 7)*64 + (bid >> 3);           // XCD-bijective swizzle (512 = 8*64)
  int t = threadIdx.x, wid = t >> 6, lane = t & 63, l15 = lane & 15, kg = lane >> 4;

  f32x4 acc[4][4];
  #pragma unroll
  for (int m = 0; m < 4; ++m)
    #pragma unroll
    for (int n = 0; n < 4; ++n) acc[m][n] = (f32x4){0.f,0.f,0.f,0.f};

  Frag A, B;

  if (q == 0){
    // direct path for p = 0..3
    for (int p = 0; p < 4; ++p){
      int lp = levelof(p);
      #pragma unroll
      for (int m = 0; m < 4; ++m)
        #pragma unroll
        for (int n = 0; n < 4; ++n) acc[m][n] = (f32x4){0.f,0.f,0.f,0.f};
      for (int k = 0; k <= lp; ++k){
        load_bfrag(B, W2b + (size_t)k*4096, l15, kg);
        load_afrag(A, H + (size_t)(p >> k)*16384, wid, l15, kg);
        mstep(acc, A, B);
      }
      epilogue(acc, p, lp, cb2, W3, y3, wid, l15, kg);
    }
    return;
  }

  const int lq = levelof(q);
  const int L  = lq + 2;                        // leaf level

  // ---- shared chain: k = 2..L, tile H[q>>(k-2)], 1-deep A prefetch ----
  {
    Frag An;
    load_afrag(A, H + (size_t)q*16384, wid, l15, kg);
    for (int k = 2; k <= L; ++k){
      if (k < L) load_afrag(An, H + (size_t)(q >> (k-1))*16384, wid, l15, kg);
      load_bfrag(B, W2b + (size_t)k*4096, l15, kg);
      mstep(acc, A, B);
      if (k < L) A = An;
    }
  }

  Frag Am;
  // mid0 (node 2q, W2[1]) + leaf0 (4q, W2[0])
  load_afrag(Am, H + (size_t)(2*q)*16384, wid, l15, kg);
  load_afrag(A,  H + (size_t)(4*q)*16384, wid, l15, kg);
  load_bfrag(B, W2b + 4096, l15, kg);           // W2[1]
  mstep(acc, Am, B);
  load_bfrag(B, W2b, l15, kg);                  // W2[0]
  mstep(acc, A, B);
  epilogue(acc, 4*q, L, cb2, W3, y3, wid, l15, kg);
  // leaf1
  negate(A); mstep(acc, A, B);
  load_afrag(A, H + (size_t)(4*q + 1)*16384, wid, l15, kg);
  mstep(acc, A, B);
  epilogue(acc, 4*q + 1, L, cb2, W3, y3, wid, l15, kg);
  // unwind leaf1 + mid0
  negate(A); mstep(acc, A, B);
  load_bfrag(B, W2b + 4096, l15, kg);           // W2[1]
  negate(Am); mstep(acc, Am, B);
  // mid1 (2q+1) + leaf2 (4q+2)
  load_afrag(Am, H + (size_t)(2*q + 1)*16384, wid, l15, kg);
  mstep(acc, Am, B);
  load_afrag(A, H + (size_t)(4*q + 2)*16384, wid, l15, kg);
  load_bfrag(B, W2b, l15, kg);                  // W2[0]
  mstep(acc, A, B);
  epilogue(acc, 4*q + 2, L, cb2, W3, y3, wid, l15, kg);
  // leaf3
  negate(A); mstep(acc, A, B);
  load_afrag(A, H + (size_t)(4*q + 3)*16384, wid, l15, kg);
  mstep(acc, A, B);
  epilogue(acc, 4*q + 3, L, cb2, W3, y3, wid, l15, kg);
}

// ---------------- K3: out[b][2p(+1)] = L[b][p]; j=0 special ------------------
__global__ __launch_bounds__(256) void k_scatter(const float* __restrict__ y3,
    const float* __restrict__ cb3, const float* __restrict__ w3h20,
    float* __restrict__ out){
  int bid = blockIdx.x;                 // 2048 = 256 b x 8 chunks
  int b = bid >> 3;
  int p = (bid & 7)*256 + threadIdx.x;
  int lp = levelof(p);
  const float* yb = y3 + (size_t)b*4095*2;
  float s0 = cb3[(lp+1)*2]     + w3h20[(lp+1)*2];
  float s1 = cb3[(lp+1)*2 + 1] + w3h20[(lp+1)*2 + 1];
  for (int k = 0; k <= lp; ++k){
    int pi = (4096 - (4096 >> k)) + (p >> k);
    s0 += yb[pi*2];
    s1 += yb[pi*2 + 1];
  }
  float4 o;
  if (p == 0){
    o.x = cb3[0] + w3h20[0];
    o.y = cb3[1] + w3h20[1];
    o.z = s0; o.w = s1;
  } else {
    o.x = s0; o.y = s1; o.z = s0; o.w = s1;
  }
  *(float4*)(out + (size_t)b*8192 + (size_t)p*4) = o;
}

extern "C" void kernel_launch(void* const* d_in, const int* in_sizes, int n_in,
                              void* d_out, int out_size, void* d_ws, size_t ws_size,
                              hipStream_t stream){
  const float* x  = (const float*)d_in[0];
  const float* W1 = (const float*)d_in[1];
  const float* b1 = (const float*)d_in[2];
  const float* W2 = (const float*)d_in[3];
  const float* b2 = (const float*)d_in[4];
  const float* W3 = (const float*)d_in[5];
  const float* b3 = (const float*)d_in[6];
  float* out = (float*)d_out;
  char* ws = (char*)d_ws;

  unsigned short* W2b   = (unsigned short*)(ws + 0);          //   106,496
  unsigned short* W1f   = (unsigned short*)(ws + 106496);     //     4,096
  float* cb1   = (float*)(ws + 110592);                       //     3,328
  float* cb2   = (float*)(ws + 113920);                       //     3,328
  float* cb3   = (float*)(ws + 117248);                       //       128
  float* w3h20 = (float*)(ws + 117376);                       //       128
  float* xT    = (float*)(ws + 117504);                       // 8,388,608
  unsigned short* H = (unsigned short*)(ws + 8506112);        // 67,108,864
  float* y3    = (float*)(ws + 75614976);                     // 8,386,560
  // total 84,001,536 B

  hipLaunchKernelGGL(k_prep,    dim3(210),  dim3(256), 0, stream, W2, W1, W3, b1, b2, b3, W2b, W1f, cb1, cb2, cb3, w3h20);
  hipLaunchKernelGGL(k_xpose,   dim3(256),  dim3(256), 0, stream, x, xT);
  hipLaunchKernelGGL(k_GH,      dim3(2048), dim3(256), 0, stream, xT, W1f, cb1, H);
  hipLaunchKernelGGL(k_F2,      dim3(512),  dim3(256), 0, stream, H, W2b, cb2, W3, y3);
  hipLaunchKernelGGL(k_scatter, dim3(2048), dim3(256), 0, stream, y3, cb3, w3h20, out);
}

// Round 5
// 162.259 us; speedup vs baseline: 1.2133x; 1.2133x over previous
//
#include <hip/hip_runtime.h>

#define UNITS 4096
#define DEPTH 13
#define BATCH 256

typedef __attribute__((ext_vector_type(8))) short s16x8;
typedef __attribute__((ext_vector_type(4))) float f32x4;
typedef __attribute__((ext_vector_type(4))) int   i32x4;

__device__ __forceinline__ unsigned short f2bf(float f){
  unsigned u = __builtin_bit_cast(unsigned, f);
  u += 0x7FFFu + ((u >> 16) & 1u);
  return (unsigned short)(u >> 16);
}
__device__ __forceinline__ int levelof(int j){ return j ? (32 - __clz(j)) : 0; }

struct FragA { s16x8 v[2][2]; };   // 16 VGPR: M=32 rows (2 m-tiles) x K=64
struct FragB { s16x8 v[2][4]; };   // 32 VGPR: N=64 x K=64

// A-frag from tiled H: idx16 = ((kk*4+kg)*256 + row)*8, row = rowbase + m*16 + l15
__device__ __forceinline__ void load_afrag(FragA& f, const unsigned short* __restrict__ Hq,
                                           int rowbase, int l15, int kg){
  #pragma unroll
  for (int kk = 0; kk < 2; ++kk)
    #pragma unroll
    for (int m = 0; m < 2; ++m)
      f.v[kk][m] = *(const s16x8*)(Hq + ((size_t)((kk*4 + kg)*256 + rowbase + m*16 + l15))*8);
}
// B-frag from frag-linear W2f: idx16 = ((kk*4+n)*64 + lane)*8 — 1KB coalesced per load
__device__ __forceinline__ void load_bfrag(FragB& f, const unsigned short* __restrict__ Wf,
                                           int lane){
  #pragma unroll
  for (int kk = 0; kk < 2; ++kk)
    #pragma unroll
    for (int n = 0; n < 4; ++n)
      f.v[kk][n] = *(const s16x8*)(Wf + ((size_t)((kk*4 + n)*64 + lane))*8);
}
__device__ __forceinline__ void mstep(f32x4 acc[2][4], const FragA& A, const FragB& B){
  #pragma unroll
  for (int kk = 0; kk < 2; ++kk)
    #pragma unroll
    for (int m = 0; m < 2; ++m)
      #pragma unroll
      for (int n = 0; n < 4; ++n)
        acc[m][n] = __builtin_amdgcn_mfma_f32_16x16x32_bf16(A.v[kk][m], B.v[kk][n], acc[m][n], 0, 0, 0);
}
__device__ __forceinline__ void negA(FragA& A){
  const i32x4 sgn = {(int)0x80008000, (int)0x80008000, (int)0x80008000, (int)0x80008000};
  #pragma unroll
  for (int kk = 0; kk < 2; ++kk)
    #pragma unroll
    for (int m = 0; m < 2; ++m){
      i32x4 t = __builtin_bit_cast(i32x4, A.v[kk][m]);
      t ^= sgn;
      A.v[kk][m] = __builtin_bit_cast(s16x8, t);
    }
}

// y3 epilogue (acc preserved): y3[tt][p] = W3[tt].relu(acc + cb2[lp+1])
__device__ __forceinline__ void epilogue(const f32x4 acc[2][4], int p, int lp,
    const float* __restrict__ cb2, const float* __restrict__ W3,
    float* __restrict__ y3, int rowbase, int l15, int kg){
  float cbv[4];
  #pragma unroll
  for (int n = 0; n < 4; ++n) cbv[n] = cb2[(lp+1)*64 + n*16 + l15];
  int tmax = 11 - lp;
  for (int tt = 0; tt <= tmax; ++tt){
    float w30[4], w31[4];
    #pragma unroll
    for (int n = 0; n < 4; ++n){
      w30[n] = W3[(tt*2 + 0)*64 + n*16 + l15];
      w31[n] = W3[(tt*2 + 1)*64 + n*16 + l15];
    }
    int off = 4096 - (4096 >> tt);
    #pragma unroll
    for (int m = 0; m < 2; ++m)
      #pragma unroll
      for (int reg = 0; reg < 4; ++reg){
        float s0 = 0.f, s1 = 0.f;
        #pragma unroll
        for (int n = 0; n < 4; ++n){
          float hv = fmaxf(acc[m][n][reg] + cbv[n], 0.f);
          s0 = fmaf(w30[n], hv, s0);
          s1 = fmaf(w31[n], hv, s1);
        }
        #pragma unroll
        for (int d = 1; d < 16; d <<= 1){
          s0 += __shfl_xor(s0, d);
          s1 += __shfl_xor(s1, d);
        }
        if (l15 == 0){
          int b = rowbase + m*16 + kg*4 + reg;
          float2 v; v.x = s0; v.y = s1;
          *(float2*)(y3 + ((size_t)b*4095 + off + p)*2) = v;
        }
      }
  }
}

// ---------------- K0: prep: W2 -> frag-linear bf16, W1 B-frags, biases -------
__global__ __launch_bounds__(256) void k_prep(const float* __restrict__ W2,
    const float* __restrict__ W1, const float* __restrict__ W3,
    const float* __restrict__ b1, const float* __restrict__ b2, const float* __restrict__ b3,
    unsigned short* __restrict__ W2f, unsigned short* __restrict__ W1f,
    float* __restrict__ cb1, float* __restrict__ cb2, float* __restrict__ cb3,
    float* __restrict__ w3h20){
  int blk = blockIdx.x, t = threadIdx.x;
  if (blk < 26){
    // W2f[((k*8 + kk*4+n)*64 + lane)*8 + e] = bf16(W2[k][n*16+l15][kk*32+kg*8+e])
    int u = blk*256 + t;                  // 0..6655
    int lane = u & 63, c = (u >> 6) & 7, k = u >> 9;
    int n = c & 3, kk = c >> 2, l15 = lane & 15, kg = lane >> 4;
    s16x8 rr;
    #pragma unroll
    for (int e = 0; e < 8; ++e)
      rr[e] = (short)f2bf(W2[((size_t)(k*64 + n*16 + l15))*64 + kk*32 + kg*8 + e]);
    *(s16x8*)(W2f + (size_t)u*8) = rr;
  } else if (blk == 26){
    // W1f: B-fragment for G GEMM: k = 2m+c -> W1[m][f][c]
    int n = t >> 6, lane = t & 63, l15 = lane & 15, kg = lane >> 4;
    int f = n*16 + l15;
    s16x8 r = {0,0,0,0,0,0,0,0};
    #pragma unroll
    for (int j = 0; j < 4; ++j){
      int m = kg*4 + j;
      if (m < DEPTH-1){
        r[2*j]   = (short)f2bf(W1[(m*64 + f)*2]);
        r[2*j+1] = (short)f2bf(W1[(m*64 + f)*2 + 1]);
      }
    }
    *(s16x8*)(W1f + (size_t)t*8) = r;
  } else {
    if (t < 64){
      float r = 0.f;
      cb1[t] = 0.f;
      for (int m = 1; m < DEPTH; ++m){ r += b1[(m-1)*64 + t]; cb1[m*64 + t] = r; }
      float r2 = 0.f;
      for (int m = 0; m < DEPTH; ++m){ r2 += b2[m*64 + t]; cb2[m*64 + t] = r2; }
    } else if (t < 66){
      int o = t - 64;
      float r = 0.f;
      for (int m = 0; m < DEPTH; ++m){ r += b3[m*2 + o]; cb3[m*2 + o] = r; }
    } else if (t >= 128 && t < 128 + DEPTH*2){
      int q = t - 128, tt = q >> 1, o = q & 1;
      float s = 0.f;
      for (int f = 0; f < 64; ++f)
        s = fmaf(W3[(tt*2 + o)*64 + f], fmaxf(b2[f], 0.f), s);  // h2[0]=relu(b2)
      w3h20[tt*2 + o] = s;
    }
  }
}

// ---------------- K0b: transpose x[b][j][2] -> xT[j][b][2] -------------------
__global__ __launch_bounds__(256) void k_xpose(const float* __restrict__ x,
                                               float* __restrict__ xT){
  __shared__ float2 tile[64][65];
  int jb = (blockIdx.x & 63) * 64;
  int bb = (blockIdx.x >> 6) * 64;
  int t = threadIdx.x;
  #pragma unroll
  for (int i = 0; i < 16; ++i){
    int idx = i*256 + t;
    int jj = idx & 63, b = idx >> 6;
    tile[jj][b] = *(const float2*)(x + (((size_t)(bb + b))*UNITS + jb + jj)*2);
  }
  __syncthreads();
  #pragma unroll
  for (int i = 0; i < 16; ++i){
    int idx = i*256 + t;
    int b = idx & 63, jj = idx >> 6;
    *(float2*)(xT + (((size_t)(jb + jj))*BATCH + bb + b)*2) = tile[jj][b];
  }
}

// ---------------- K1: H[p] = relu(sum_m W1[m].x[p>>m] + cb1[lvl(p)+1]) -------
// Stored in MFMA-A-fragment tiled layout: idx16 = ((kk*4+kg)*256 + row)*8
__global__ __launch_bounds__(256) void k_GH(const float* __restrict__ xT,
    const unsigned short* __restrict__ W1f, const float* __restrict__ cb1,
    unsigned short* __restrict__ H){
  __shared__ unsigned short tile[BATCH*64];  // 32 KiB
  int p = blockIdx.x;
  int lvl = levelof(p);
  int t = threadIdx.x, wid = t >> 6, lane = t & 63, l15 = lane & 15, kg = lane >> 4;

  s16x8 af[4];
  #pragma unroll
  for (int m = 0; m < 4; ++m){
    int b = wid*64 + m*16 + l15;
    s16x8 r = {0,0,0,0,0,0,0,0};
    #pragma unroll
    for (int j = 0; j < 4; ++j){
      int mm = kg*4 + j;
      if (mm <= lvl){
        float2 xv = *(const float2*)(xT + ((size_t)(p >> mm)*BATCH + b)*2);
        r[2*j]   = (short)f2bf(xv.x);
        r[2*j+1] = (short)f2bf(xv.y);
      }
    }
    af[m] = r;
  }
  f32x4 acc[4][4];
  #pragma unroll
  for (int m = 0; m < 4; ++m)
    #pragma unroll
    for (int n = 0; n < 4; ++n) acc[m][n] = (f32x4){0.f,0.f,0.f,0.f};
  #pragma unroll
  for (int n = 0; n < 4; ++n){
    s16x8 bf = *(const s16x8*)(W1f + ((size_t)n*64 + lane)*8);
    #pragma unroll
    for (int m = 0; m < 4; ++m)
      acc[m][n] = __builtin_amdgcn_mfma_f32_16x16x32_bf16(af[m], bf, acc[m][n], 0, 0, 0);
  }
  int lvl1 = lvl + 1;
  float cbv[4];
  #pragma unroll
  for (int n = 0; n < 4; ++n) cbv[n] = cb1[lvl1*64 + n*16 + l15];
  #pragma unroll
  for (int m = 0; m < 4; ++m)
    #pragma unroll
    for (int n = 0; n < 4; ++n)
      #pragma unroll
      for (int i = 0; i < 4; ++i){
        int row = wid*64 + m*16 + kg*4 + i;
        int col = n*16 + l15;
        float v = fmaxf(acc[m][n][i] + cbv[n], 0.f);
        *(unsigned short*)((char*)tile + ((row*128 + col*2) ^ ((row & 7) << 4))) = f2bf(v);
      }
  __syncthreads();
  #pragma unroll
  for (int i = 0; i < 8; ++i){
    s16x8 v = *(const s16x8*)((const char*)tile + ((t*128 + i*16) ^ ((t & 7) << 4)));
    *(s16x8*)(H + (size_t)p*16384 + ((size_t)i*256 + t)*8) = v;
  }
}

// ---------------- K2: quad-DFS F + fused y3, M=128 per block -----------------
// Block (q, half): leaves {4q..4q+3} at level L=lq+2 share chain sum_{k>=2}.
// DFS via add/subtract MFMA steps; 1024 blocks, no spill (acc 32 + frags 64 VGPR).
__global__ __launch_bounds__(256, 4) void k_F3(const unsigned short* __restrict__ H,
    const unsigned short* __restrict__ W2f, const float* __restrict__ cb2,
    const float* __restrict__ W3, float* __restrict__ y3){
  int bid = blockIdx.x;
  int xcd = bid & 7, r = bid >> 3;
  int q = xcd*64 + (r >> 1), half = r & 1;    // XCD-bijective: XCD x owns quads [64x,64x+64)
  int t = threadIdx.x, wid = t >> 6, lane = t & 63, l15 = lane & 15, kg = lane >> 4;
  int rowbase = half*128 + wid*32;

  f32x4 acc[2][4];
  #pragma unroll
  for (int m = 0; m < 2; ++m)
    #pragma unroll
    for (int n = 0; n < 4; ++n) acc[m][n] = (f32x4){0.f,0.f,0.f,0.f};

  FragA A, Am; FragB B;

  if (q == 0){
    for (int p = 0; p < 4; ++p){
      int lp = levelof(p);
      #pragma unroll
      for (int m = 0; m < 2; ++m)
        #pragma unroll
        for (int n = 0; n < 4; ++n) acc[m][n] = (f32x4){0.f,0.f,0.f,0.f};
      for (int k = 0; k <= lp; ++k){
        load_bfrag(B, W2f + (size_t)k*4096, lane);
        load_afrag(A, H + (size_t)(p >> k)*16384, rowbase, l15, kg);
        mstep(acc, A, B);
      }
      epilogue(acc, p, lp, cb2, W3, y3, rowbase, l15, kg);
    }
    return;
  }

  const int lq = levelof(q);
  const int L  = lq + 2;

  // shared chain: k = 2..L over tiles H[q>>(k-2)]
  for (int k = 2; k <= L; ++k){
    load_afrag(A, H + (size_t)(q >> (k-2))*16384, rowbase, l15, kg);
    load_bfrag(B, W2f + (size_t)k*4096, lane);
    mstep(acc, A, B);
  }

  // DFS over {4q..4q+3}
  load_afrag(Am, H + (size_t)(2*q)*16384, rowbase, l15, kg);
  load_afrag(A,  H + (size_t)(4*q)*16384, rowbase, l15, kg);
  load_bfrag(B, W2f + 4096, lane);              // W2[1]
  mstep(acc, Am, B);
  load_bfrag(B, W2f, lane);                     // W2[0]
  mstep(acc, A, B);
  epilogue(acc, 4*q, L, cb2, W3, y3, rowbase, l15, kg);
  // leaf1
  negA(A); mstep(acc, A, B);
  load_afrag(A, H + (size_t)(4*q + 1)*16384, rowbase, l15, kg);
  mstep(acc, A, B);
  epilogue(acc, 4*q + 1, L, cb2, W3, y3, rowbase, l15, kg);
  // unwind leaf1 + mid0, enter mid1 + leaf2
  negA(A); mstep(acc, A, B);
  load_bfrag(B, W2f + 4096, lane);              // W2[1]
  negA(Am); mstep(acc, Am, B);
  load_afrag(Am, H + (size_t)(2*q + 1)*16384, rowbase, l15, kg);
  mstep(acc, Am, B);
  load_afrag(A, H + (size_t)(4*q + 2)*16384, rowbase, l15, kg);
  load_bfrag(B, W2f, lane);                     // W2[0]
  mstep(acc, A, B);
  epilogue(acc, 4*q + 2, L, cb2, W3, y3, rowbase, l15, kg);
  // leaf3
  negA(A); mstep(acc, A, B);
  load_afrag(A, H + (size_t)(4*q + 3)*16384, rowbase, l15, kg);
  mstep(acc, A, B);
  epilogue(acc, 4*q + 3, L, cb2, W3, y3, rowbase, l15, kg);
}

// ---------------- K3: out[b][2p(+1)] = L[b][p]; j=0 special ------------------
__global__ __launch_bounds__(256) void k_scatter(const float* __restrict__ y3,
    const float* __restrict__ cb3, const float* __restrict__ w3h20,
    float* __restrict__ out){
  int bid = blockIdx.x;                 // 2048 = 256 b x 8 chunks
  int b = bid >> 3;
  int p = (bid & 7)*256 + threadIdx.x;
  int lp = levelof(p);
  const float* yb = y3 + (size_t)b*4095*2;
  float s0 = cb3[(lp+1)*2]     + w3h20[(lp+1)*2];
  float s1 = cb3[(lp+1)*2 + 1] + w3h20[(lp+1)*2 + 1];
  for (int k = 0; k <= lp; ++k){
    int pi = (4096 - (4096 >> k)) + (p >> k);
    s0 += yb[pi*2];
    s1 += yb[pi*2 + 1];
  }
  float4 o;
  if (p == 0){
    o.x = cb3[0] + w3h20[0];
    o.y = cb3[1] + w3h20[1];
    o.z = s0; o.w = s1;
  } else {
    o.x = s0; o.y = s1; o.z = s0; o.w = s1;
  }
  *(float4*)(out + (size_t)b*8192 + (size_t)p*4) = o;
}

extern "C" void kernel_launch(void* const* d_in, const int* in_sizes, int n_in,
                              void* d_out, int out_size, void* d_ws, size_t ws_size,
                              hipStream_t stream){
  const float* x  = (const float*)d_in[0];
  const float* W1 = (const float*)d_in[1];
  const float* b1 = (const float*)d_in[2];
  const float* W2 = (const float*)d_in[3];
  const float* b2 = (const float*)d_in[4];
  const float* W3 = (const float*)d_in[5];
  const float* b3 = (const float*)d_in[6];
  float* out = (float*)d_out;
  char* ws = (char*)d_ws;

  unsigned short* W2f   = (unsigned short*)(ws + 0);          //   106,496
  unsigned short* W1f   = (unsigned short*)(ws + 106496);     //     4,096
  float* cb1   = (float*)(ws + 110592);                       //     3,328
  float* cb2   = (float*)(ws + 113920);                       //     3,328
  float* cb3   = (float*)(ws + 117248);                       //       128
  float* w3h20 = (float*)(ws + 117376);                       //       128
  float* xT    = (float*)(ws + 117504);                       // 8,388,608
  unsigned short* H = (unsigned short*)(ws + 8506112);        // 67,108,864
  float* y3    = (float*)(ws + 75614976);                     // 8,386,560
  // total 84,001,536 B

  hipLaunchKernelGGL(k_prep,    dim3(28),   dim3(256), 0, stream, W2, W1, W3, b1, b2, b3, W2f, W1f, cb1, cb2, cb3, w3h20);
  hipLaunchKernelGGL(k_xpose,   dim3(256),  dim3(256), 0, stream, x, xT);
  hipLaunchKernelGGL(k_GH,      dim3(2048), dim3(256), 0, stream, xT, W1f, cb1, H);
  hipLaunchKernelGGL(k_F3,      dim3(1024), dim3(256), 0, stream, H, W2f, cb2, W3, y3);
  hipLaunchKernelGGL(k_scatter, dim3(2048), dim3(256), 0, stream, y3, cb3, w3h20, out);
}